// Round 1
// baseline (749.497 us; speedup 1.0000x reference)
//
#include <hip/hip_runtime.h>
#include <hip/hip_bf16.h>
#include <cstdint>
#include <cstddef>

// GATv2Conv forward, N=100000 nodes, E=1.6M edges, IN=128, H=4, C=32 (H*C=128).
//
// Pipeline (all fp32):
//   1) gemm128_k  x@W_l -> xl, x@W_r -> xr      (64-row tiles, 4x8 reg blocking)
//   2) counting-sort edges by dst:
//        hist_k -> scan1_k -> scan2_k -> scan3_k -> scatter_k   (CSR by dst)
//   3) agg_k: one wave per dst node, fused online-softmax over its edge list:
//        e = att . leaky_relu(xl[src] + xr[dst]); running (m,l,acc) rescale;
//        out = acc/(l+EPS) + bias.   One 512B coalesced gather per edge,
//        per-head reduction via shfl_xor within 16-lane groups, no atomics.

#define NEG_SLOPE 0.2f
#define EPS_F 1e-16f

// ---------------- GEMM: C[nrows x 128] = A[nrows x 128] * W[128 x 128] ----------------
__global__ __launch_bounds__(256) void gemm128_k(const float* __restrict__ A,
                                                 const float* __restrict__ W,
                                                 float* __restrict__ C, int nrows) {
    __shared__ float xs[64][68];    // 64 rows x 64 k, +4 pad (17 KB)
    __shared__ float wsh[64][128];  // 64 k x 128 cols (32 KB)

    const int tid = threadIdx.x;
    const int ty = tid >> 4;   // 0..15 -> 4 rows each
    const int tx = tid & 15;   // 0..15 -> 8 cols each
    const int row0 = blockIdx.x * 64;

    float acc[4][8];
#pragma unroll
    for (int i = 0; i < 4; ++i)
#pragma unroll
        for (int j = 0; j < 8; ++j) acc[i][j] = 0.f;

    for (int kc = 0; kc < 2; ++kc) {
        // load x chunk: 64 rows x 64 k = 1024 float4
#pragma unroll
        for (int i = 0; i < 4; ++i) {
            int idx = tid + i * 256;           // 0..1023
            int r = idx >> 4, kq = idx & 15;
            int gr = row0 + r;
            gr = gr < nrows ? gr : nrows - 1;  // clamp (extra rows computed, never stored)
            float4 v = *(const float4*)(A + (size_t)gr * 128 + kc * 64 + kq * 4);
            *(float4*)(&xs[r][kq * 4]) = v;
        }
        // load W chunk: 64 k x 128 cols = 2048 float4
#pragma unroll
        for (int i = 0; i < 8; ++i) {
            int idx = tid + i * 256;           // 0..2047
            int k = idx >> 5, c4 = idx & 31;
            *(float4*)(&wsh[k][c4 * 4]) =
                *(const float4*)(W + (size_t)(kc * 64 + k) * 128 + c4 * 4);
        }
        __syncthreads();

#pragma unroll 8
        for (int k = 0; k < 64; ++k) {
            float av[4];
            av[0] = xs[ty * 4 + 0][k];
            av[1] = xs[ty * 4 + 1][k];
            av[2] = xs[ty * 4 + 2][k];
            av[3] = xs[ty * 4 + 3][k];
            float4 w0 = *(float4*)(&wsh[k][tx * 8]);
            float4 w1 = *(float4*)(&wsh[k][tx * 8 + 4]);
            float wv[8] = {w0.x, w0.y, w0.z, w0.w, w1.x, w1.y, w1.z, w1.w};
#pragma unroll
            for (int i = 0; i < 4; ++i)
#pragma unroll
                for (int j = 0; j < 8; ++j) acc[i][j] = fmaf(av[i], wv[j], acc[i][j]);
        }
        __syncthreads();
    }

#pragma unroll
    for (int i = 0; i < 4; ++i) {
        int gr = row0 + ty * 4 + i;
        if (gr < nrows) {
            float4 o0 = {acc[i][0], acc[i][1], acc[i][2], acc[i][3]};
            float4 o1 = {acc[i][4], acc[i][5], acc[i][6], acc[i][7]};
            *(float4*)(C + (size_t)gr * 128 + tx * 8) = o0;
            *(float4*)(C + (size_t)gr * 128 + tx * 8 + 4) = o1;
        }
    }
}

// ---------------- counting sort of edges by dst ----------------
__global__ void hist_k(const int* __restrict__ dst, int E, int* __restrict__ cnt) {
    int e = blockIdx.x * blockDim.x + threadIdx.x;
    if (e < E) atomicAdd(&cnt[dst[e]], 1);
}

#define CHUNK 128
__global__ void scan1_k(const int* __restrict__ cnt, int n,
                        int* __restrict__ partial, int nch) {
    int c = blockIdx.x * blockDim.x + threadIdx.x;
    if (c >= nch) return;
    int base = c * CHUNK;
    int lim = min(CHUNK, n - base);
    int s = 0;
    for (int i = 0; i < lim; ++i) s += cnt[base + i];
    partial[c] = s;
}

__global__ void scan2_k(int* partial, int nch) {
    if (threadIdx.x == 0 && blockIdx.x == 0) {
        int acc = 0;
        for (int c = 0; c < nch; ++c) {
            int t = partial[c];
            partial[c] = acc;
            acc += t;
        }
    }
}

__global__ void scan3_k(const int* __restrict__ cnt, const int* __restrict__ partial,
                        int n, int nch,
                        int* __restrict__ row_start, int* __restrict__ cursor) {
    int c = blockIdx.x * blockDim.x + threadIdx.x;
    if (c >= nch) return;
    int base = c * CHUNK;
    int lim = min(CHUNK, n - base);
    int run = partial[c];
    for (int i = 0; i < lim; ++i) {
        row_start[base + i] = run;
        cursor[base + i] = run;
        run += cnt[base + i];
    }
    if (c == nch - 1) row_start[n] = run;  // == E
}

__global__ void scatter_k(const int* __restrict__ src, const int* __restrict__ dst, int E,
                          int* __restrict__ cursor, int* __restrict__ src_sorted) {
    int e = blockIdx.x * blockDim.x + threadIdx.x;
    if (e < E) {
        int d = dst[e];
        int pos = atomicAdd(&cursor[d], 1);
        src_sorted[pos] = src[e];
    }
}

// ---------------- fused online-softmax aggregation: one wave per dst node ----------------
// lane -> channels (2*lane, 2*lane+1); head = lane>>4, so each 16-lane shfl group
// is exactly one head's 32 channels.
__global__ __launch_bounds__(256) void agg_k(const float* __restrict__ xl,
                                             const float* __restrict__ xr,
                                             const float* __restrict__ att,
                                             const float* __restrict__ bias,
                                             const int* __restrict__ row_start,
                                             const int* __restrict__ src_sorted,
                                             int n, float* __restrict__ out) {
    const int wave = threadIdx.x >> 6;
    const int lane = threadIdx.x & 63;
    const int i = blockIdx.x * 4 + wave;
    if (i >= n) return;

    const int c0 = lane * 2;
    const float2 xr2 = *(const float2*)(xr + (size_t)i * 128 + c0);
    const float2 at2 = *(const float2*)(att + c0);

    float m = -INFINITY, l = 0.f, a0 = 0.f, a1 = 0.f;
    const int k0 = row_start[i];
    const int k1 = row_start[i + 1];

    for (int k = k0; k < k1; ++k) {
        int s = src_sorted[k];
        float2 xl2 = *(const float2*)(xl + (size_t)s * 128 + c0);
        float h0 = xl2.x + xr2.x;
        float h1 = xl2.y + xr2.y;
        h0 = h0 > 0.f ? h0 : NEG_SLOPE * h0;
        h1 = h1 > 0.f ? h1 : NEG_SLOPE * h1;
        float p = fmaf(h0, at2.x, h1 * at2.y);
        // reduce over the 16 lanes of this head
        p += __shfl_xor(p, 1);
        p += __shfl_xor(p, 2);
        p += __shfl_xor(p, 4);
        p += __shfl_xor(p, 8);
        // online softmax update
        float mn = fmaxf(m, p);
        float sc = __expf(m - mn);   // exp(-inf)=0 on first edge
        float w  = __expf(p - mn);
        l  = fmaf(l, sc, w);
        a0 = fmaf(a0, sc, w * xl2.x);
        a1 = fmaf(a1, sc, w * xl2.y);
        m = mn;
    }

    float inv = 1.f / (l + EPS_F);   // zero-degree node -> 0/(1e-16) = 0, matches ref
    float o0 = fmaf(a0, inv, bias[c0]);
    float o1 = fmaf(a1, inv, bias[c0 + 1]);
    float2 o = {o0, o1};
    *(float2*)(out + (size_t)i * 128 + c0) = o;
}

// ---------------- launch ----------------
extern "C" void kernel_launch(void* const* d_in, const int* in_sizes, int n_in,
                              void* d_out, int out_size, void* d_ws, size_t ws_size,
                              hipStream_t stream) {
    const float* x    = (const float*)d_in[0];
    const int*   ei   = (const int*)d_in[1];
    const float* W_l  = (const float*)d_in[2];
    const float* W_r  = (const float*)d_in[3];
    const float* att  = (const float*)d_in[4];
    const float* bias = (const float*)d_in[5];
    float* out = (float*)d_out;

    const int N = in_sizes[0] / 128;
    const int E = in_sizes[1] / 2;
    const int* src = ei;
    const int* dst = ei + E;

    // workspace layout (16B-aligned slabs), total ~110 MB
    char* ws = (char*)d_ws;
    size_t off = 0;
    auto alloc = [&](size_t bytes) {
        void* p = ws + off;
        off += (bytes + 15) & ~(size_t)15;
        return p;
    };
    float* xl        = (float*)alloc((size_t)N * 128 * 4);
    float* xr        = (float*)alloc((size_t)N * 128 * 4);
    int*   cnt       = (int*)alloc((size_t)N * 4);
    int*   row_start = (int*)alloc((size_t)(N + 1) * 4);
    int*   cursor    = (int*)alloc((size_t)N * 4);
    const int nch = (N + CHUNK - 1) / CHUNK;
    int*   partial   = (int*)alloc((size_t)nch * 4);
    int*   src_sorted= (int*)alloc((size_t)E * 4);
    (void)ws_size;

    hipMemsetAsync(cnt, 0, (size_t)N * 4, stream);

    const int gB = (N + 63) / 64;
    gemm128_k<<<gB, 256, 0, stream>>>(x, W_l, xl, N);
    gemm128_k<<<gB, 256, 0, stream>>>(x, W_r, xr, N);

    hist_k<<<(E + 255) / 256, 256, 0, stream>>>(dst, E, cnt);
    scan1_k<<<(nch + 255) / 256, 256, 0, stream>>>(cnt, N, partial, nch);
    scan2_k<<<1, 1, 0, stream>>>(partial, nch);
    scan3_k<<<(nch + 255) / 256, 256, 0, stream>>>(cnt, partial, N, nch, row_start, cursor);
    scatter_k<<<(E + 255) / 256, 256, 0, stream>>>(src, dst, E, cursor, src_sorted);

    agg_k<<<(N + 3) / 4, 256, 0, stream>>>(xl, xr, att, bias, row_start, src_sorted, N, out);
}

// Round 2
// 494.845 us; speedup vs baseline: 1.5146x; 1.5146x over previous
//
#include <hip/hip_runtime.h>
#include <hip/hip_bf16.h>
#include <cstdint>
#include <cstddef>

// GATv2Conv forward, N=100000, E=1.6M, IN=128, H=4, C=32 (H*C=128).
//
// Pipeline:
//   1) gemm2_k : fused  x@W_l -> xl , x@W_r -> xr  (fp32 math, bf16 stores)
//   2) counting-sort edges by dst: hist -> scanA -> scanB -> scanC -> scatter
//   3) agg_k   : one wave per dst node, fused online-softmax over its edges,
//                4-way edge ILP (4 independent (m,l,acc) states, merged at end).
//                Gathers are bf16 (4 B/lane/edge = 256 B/wave/edge).

#define NEG_SLOPE 0.2f
#define EPS_F 1e-16f

static __device__ __forceinline__ unsigned f2bf(float f) {
    unsigned u = __float_as_uint(f);
    return (u + 0x7fffu + ((u >> 16) & 1u)) >> 16;   // RNE
}
static __device__ __forceinline__ float bf2f(unsigned h) {
    return __uint_as_float(h << 16);
}

// ------------- fused GEMM: xl = A*Wl, xr = A*Wr ; A[nrows x 128], W[128 x 128] -------------
// 64-row tiles, k-chunks of 32, 4x(4+4) reg blocking per thread, bf16-packed epilogue.
__global__ __launch_bounds__(256) void gemm2_k(const float* __restrict__ A,
                                               const float* __restrict__ Wl,
                                               const float* __restrict__ Wr,
                                               unsigned* __restrict__ xlb,
                                               unsigned* __restrict__ xrb, int nrows) {
    __shared__ float xs[64][36];    // 64 rows x 32 k (+4 pad)
    __shared__ float wls[32][128];
    __shared__ float wrs[32][128];

    const int tid = threadIdx.x;
    const int ty = tid >> 4;   // 0..15 -> 4 rows
    const int tx = tid & 15;   // 0..15 -> cols tx*4..+3 and 64+tx*4..+3
    const int row0 = blockIdx.x * 64;

    float accl[4][8], accr[4][8];
#pragma unroll
    for (int i = 0; i < 4; ++i)
#pragma unroll
        for (int j = 0; j < 8; ++j) { accl[i][j] = 0.f; accr[i][j] = 0.f; }

    for (int kc = 0; kc < 4; ++kc) {
        // x chunk: 64 rows x 32 k = 512 float4 -> 2/thread
#pragma unroll
        for (int i = 0; i < 2; ++i) {
            int idx = tid + i * 256;
            int r = idx >> 3, kq = idx & 7;
            int gr = row0 + r;
            gr = gr < nrows ? gr : nrows - 1;
            *(float4*)(&xs[r][kq * 4]) = *(const float4*)(A + (size_t)gr * 128 + kc * 32 + kq * 4);
        }
        // W chunks: 32 k x 128 cols = 1024 float4 each -> 4/thread each
#pragma unroll
        for (int i = 0; i < 4; ++i) {
            int idx = tid + i * 256;
            int k = idx >> 5, c4 = idx & 31;
            *(float4*)(&wls[k][c4 * 4]) = *(const float4*)(Wl + (size_t)(kc * 32 + k) * 128 + c4 * 4);
            *(float4*)(&wrs[k][c4 * 4]) = *(const float4*)(Wr + (size_t)(kc * 32 + k) * 128 + c4 * 4);
        }
        __syncthreads();

#pragma unroll 8
        for (int k = 0; k < 32; ++k) {
            float av[4];
            av[0] = xs[ty * 4 + 0][k];
            av[1] = xs[ty * 4 + 1][k];
            av[2] = xs[ty * 4 + 2][k];
            av[3] = xs[ty * 4 + 3][k];
            float4 l0 = *(float4*)(&wls[k][tx * 4]);
            float4 l1 = *(float4*)(&wls[k][64 + tx * 4]);
            float4 r0 = *(float4*)(&wrs[k][tx * 4]);
            float4 r1 = *(float4*)(&wrs[k][64 + tx * 4]);
            float lw[8] = {l0.x, l0.y, l0.z, l0.w, l1.x, l1.y, l1.z, l1.w};
            float rw[8] = {r0.x, r0.y, r0.z, r0.w, r1.x, r1.y, r1.z, r1.w};
#pragma unroll
            for (int i = 0; i < 4; ++i)
#pragma unroll
                for (int j = 0; j < 8; ++j) {
                    accl[i][j] = fmaf(av[i], lw[j], accl[i][j]);
                    accr[i][j] = fmaf(av[i], rw[j], accr[i][j]);
                }
        }
        __syncthreads();
    }

#pragma unroll
    for (int i = 0; i < 4; ++i) {
        int gr = row0 + ty * 4 + i;
        if (gr < nrows) {
            // cols tx*4..+3 -> uints [gr*64 + tx*2, +1]; cols 64+tx*4..+3 -> [gr*64+32+tx*2, +1]
            uint2 la = {f2bf(accl[i][0]) | (f2bf(accl[i][1]) << 16),
                        f2bf(accl[i][2]) | (f2bf(accl[i][3]) << 16)};
            uint2 lb = {f2bf(accl[i][4]) | (f2bf(accl[i][5]) << 16),
                        f2bf(accl[i][6]) | (f2bf(accl[i][7]) << 16)};
            uint2 ra = {f2bf(accr[i][0]) | (f2bf(accr[i][1]) << 16),
                        f2bf(accr[i][2]) | (f2bf(accr[i][3]) << 16)};
            uint2 rb = {f2bf(accr[i][4]) | (f2bf(accr[i][5]) << 16),
                        f2bf(accr[i][6]) | (f2bf(accr[i][7]) << 16)};
            *(uint2*)(xlb + (size_t)gr * 64 + tx * 2) = la;
            *(uint2*)(xlb + (size_t)gr * 64 + 32 + tx * 2) = lb;
            *(uint2*)(xrb + (size_t)gr * 64 + tx * 2) = ra;
            *(uint2*)(xrb + (size_t)gr * 64 + 32 + tx * 2) = rb;
        }
    }
}

// ---------------- counting sort of edges by dst (parallel 2-level scan) ----------------
__global__ void hist_k(const int* __restrict__ dst, int E, int* __restrict__ cnt) {
    int e = blockIdx.x * blockDim.x + threadIdx.x;
    if (e < E) atomicAdd(&cnt[dst[e]], 1);
}

#define SCAN_B 256
// per-block exclusive scan of cnt -> row_start (in-block), block sums -> bsum
__global__ __launch_bounds__(SCAN_B) void scanA_k(const int* __restrict__ cnt, int n,
                                                  int* __restrict__ row_start,
                                                  int* __restrict__ bsum) {
    const int tid = threadIdx.x, lane = tid & 63, wid = tid >> 6;
    const int g = blockIdx.x * SCAN_B + tid;
    int v = (g < n) ? cnt[g] : 0;
    int inc = v;
#pragma unroll
    for (int d = 1; d < 64; d <<= 1) {
        int t = __shfl_up(inc, d);
        if (lane >= d) inc += t;
    }
    __shared__ int wsum[SCAN_B / 64];
    if (lane == 63) wsum[wid] = inc;
    __syncthreads();
    int add = 0;
    for (int w = 0; w < wid; ++w) add += wsum[w];
    inc += add;
    if (g < n) row_start[g] = inc - v;  // exclusive within block
    if (tid == SCAN_B - 1) bsum[blockIdx.x] = inc;
}

// single-block exclusive scan of bsum (nb <= 512)
__global__ __launch_bounds__(512) void scanB_k(int* __restrict__ bsum, int nb) {
    const int tid = threadIdx.x, lane = tid & 63, wid = tid >> 6;
    int v = (tid < nb) ? bsum[tid] : 0;
    int inc = v;
#pragma unroll
    for (int d = 1; d < 64; d <<= 1) {
        int t = __shfl_up(inc, d);
        if (lane >= d) inc += t;
    }
    __shared__ int wsum[8];
    if (lane == 63) wsum[wid] = inc;
    __syncthreads();
    int add = 0;
    for (int w = 0; w < wid; ++w) add += wsum[w];
    inc += add;
    if (tid < nb) bsum[tid] = inc - v;  // exclusive
}

__global__ __launch_bounds__(SCAN_B) void scanC_k(int* __restrict__ row_start,
                                                  const int* __restrict__ bsum,
                                                  int* __restrict__ cursor, int n, int E) {
    const int g = blockIdx.x * SCAN_B + threadIdx.x;
    if (g < n) {
        int v = row_start[g] + bsum[blockIdx.x];
        row_start[g] = v;
        cursor[g] = v;
    }
    if (g == 0) row_start[n] = E;
}

__global__ void scatter_k(const int* __restrict__ src, const int* __restrict__ dst, int E,
                          int* __restrict__ cursor, int* __restrict__ src_sorted) {
    int e = blockIdx.x * blockDim.x + threadIdx.x;
    if (e < E) {
        int d = dst[e];
        int pos = atomicAdd(&cursor[d], 1);
        src_sorted[pos] = src[e];
    }
}

// ---------------- fused online-softmax aggregation, 4-way edge ILP ----------------
// lane -> channels (2*lane, 2*lane+1); head = lane>>4; per-head reduce = shfl_xor {1,2,4,8}.
__global__ __launch_bounds__(256) void agg_k(const unsigned* __restrict__ xlb,
                                             const unsigned* __restrict__ xrb,
                                             const float* __restrict__ att,
                                             const float* __restrict__ bias,
                                             const int* __restrict__ row_start,
                                             const int* __restrict__ src_sorted,
                                             int n, float* __restrict__ out) {
    const int wave = threadIdx.x >> 6;
    const int lane = threadIdx.x & 63;
    const int i = blockIdx.x * 4 + wave;
    if (i >= n) return;

    const int c0 = lane * 2;
    unsigned xrv = xrb[(size_t)i * 64 + lane];
    const float xr0 = bf2f(xrv & 0xffffu), xr1 = bf2f(xrv >> 16);
    const float at0 = att[c0], at1 = att[c0 + 1];

    const int k0 = row_start[i];
    const int k1 = row_start[i + 1];

    float m[4], l[4], A0[4], A1[4];
#pragma unroll
    for (int u = 0; u < 4; ++u) { m[u] = -INFINITY; l[u] = 0.f; A0[u] = 0.f; A1[u] = 0.f; }

    int k = k0;
    for (; k + 4 <= k1; k += 4) {
        int s[4];
#pragma unroll
        for (int u = 0; u < 4; ++u) s[u] = src_sorted[k + u];
        unsigned v[4];
#pragma unroll
        for (int u = 0; u < 4; ++u) v[u] = xlb[(size_t)s[u] * 64 + lane];
        float x0[4], x1[4], p[4];
#pragma unroll
        for (int u = 0; u < 4; ++u) {
            x0[u] = bf2f(v[u] & 0xffffu);
            x1[u] = bf2f(v[u] >> 16);
            float h0 = x0[u] + xr0;
            float h1 = x1[u] + xr1;
            h0 = h0 > 0.f ? h0 : NEG_SLOPE * h0;
            h1 = h1 > 0.f ? h1 : NEG_SLOPE * h1;
            p[u] = fmaf(h0, at0, h1 * at1);
        }
#pragma unroll
        for (int d = 1; d < 16; d <<= 1) {
#pragma unroll
            for (int u = 0; u < 4; ++u) p[u] += __shfl_xor(p[u], d);
        }
#pragma unroll
        for (int u = 0; u < 4; ++u) {
            float mn = fmaxf(m[u], p[u]);
            float sc = __expf(m[u] - mn);
            float w  = __expf(p[u] - mn);
            l[u]  = fmaf(l[u], sc, w);
            A0[u] = fmaf(A0[u], sc, w * x0[u]);
            A1[u] = fmaf(A1[u], sc, w * x1[u]);
            m[u] = mn;
        }
    }
    for (; k < k1; ++k) {
        int s = src_sorted[k];
        unsigned v = xlb[(size_t)s * 64 + lane];
        float x0 = bf2f(v & 0xffffu), x1 = bf2f(v >> 16);
        float h0 = x0 + xr0, h1 = x1 + xr1;
        h0 = h0 > 0.f ? h0 : NEG_SLOPE * h0;
        h1 = h1 > 0.f ? h1 : NEG_SLOPE * h1;
        float p = fmaf(h0, at0, h1 * at1);
        p += __shfl_xor(p, 1);
        p += __shfl_xor(p, 2);
        p += __shfl_xor(p, 4);
        p += __shfl_xor(p, 8);
        float mn = fmaxf(m[0], p);
        float sc = __expf(m[0] - mn);
        float w  = __expf(p - mn);
        l[0]  = fmaf(l[0], sc, w);
        A0[0] = fmaf(A0[0], sc, w * x0);
        A1[0] = fmaf(A1[0], sc, w * x1);
        m[0] = mn;
    }

    // merge states 1..3 into 0 (skip never-touched states to avoid inf-inf NaN)
#pragma unroll
    for (int u = 1; u < 4; ++u) {
        if (m[u] > -INFINITY) {
            float mn = fmaxf(m[0], m[u]);
            float s0 = __expf(m[0] - mn);
            float s1 = __expf(m[u] - mn);
            l[0]  = l[0] * s0 + l[u] * s1;
            A0[0] = A0[0] * s0 + A0[u] * s1;
            A1[0] = A1[0] * s0 + A1[u] * s1;
            m[0] = mn;
        }
    }

    float inv = 1.f / (l[0] + EPS_F);
    float2 o = {fmaf(A0[0], inv, bias[c0]), fmaf(A1[0], inv, bias[c0 + 1])};
    *(float2*)(out + (size_t)i * 128 + c0) = o;
}

// ---------------- launch ----------------
extern "C" void kernel_launch(void* const* d_in, const int* in_sizes, int n_in,
                              void* d_out, int out_size, void* d_ws, size_t ws_size,
                              hipStream_t stream) {
    const float* x    = (const float*)d_in[0];
    const int*   ei   = (const int*)d_in[1];
    const float* W_l  = (const float*)d_in[2];
    const float* W_r  = (const float*)d_in[3];
    const float* att  = (const float*)d_in[4];
    const float* bias = (const float*)d_in[5];
    float* out = (float*)d_out;

    const int N = in_sizes[0] / 128;
    const int E = in_sizes[1] / 2;
    const int* src = ei;
    const int* dst = ei + E;

    char* ws = (char*)d_ws;
    size_t off = 0;
    auto alloc = [&](size_t bytes) {
        void* p = ws + off;
        off += (bytes + 15) & ~(size_t)15;
        return p;
    };
    unsigned* xlb     = (unsigned*)alloc((size_t)N * 64 * 4);   // bf16-packed
    unsigned* xrb     = (unsigned*)alloc((size_t)N * 64 * 4);
    int* cnt          = (int*)alloc((size_t)N * 4);
    int* row_start    = (int*)alloc((size_t)(N + 1) * 4);
    int* cursor       = (int*)alloc((size_t)N * 4);
    const int nsb = (N + SCAN_B - 1) / SCAN_B;                  // scan blocks (391)
    int* bsum         = (int*)alloc((size_t)nsb * 4);
    int* src_sorted   = (int*)alloc((size_t)E * 4);
    (void)ws_size;

    hipMemsetAsync(cnt, 0, (size_t)N * 4, stream);

    gemm2_k<<<(N + 63) / 64, 256, 0, stream>>>(x, W_l, W_r, xlb, xrb, N);

    hist_k<<<(E + 255) / 256, 256, 0, stream>>>(dst, E, cnt);
    scanA_k<<<nsb, SCAN_B, 0, stream>>>(cnt, N, row_start, bsum);
    scanB_k<<<1, 512, 0, stream>>>(bsum, nsb);
    scanC_k<<<nsb, SCAN_B, 0, stream>>>(row_start, bsum, cursor, N, E);
    scatter_k<<<(E + 255) / 256, 256, 0, stream>>>(src, dst, E, cursor, src_sorted);

    agg_k<<<(N + 3) / 4, 256, 0, stream>>>(xlb, xrb, att, bias, row_start, src_sorted, N, out);
}

// Round 3
// 458.222 us; speedup vs baseline: 1.6357x; 1.0799x over previous
//
#include <hip/hip_runtime.h>
#include <hip/hip_bf16.h>
#include <cstdint>
#include <cstddef>

// GATv2Conv forward, N=100000, E=1.6M, IN=128, H=4, C=32 (H*C=128).
//
// Pipeline:
//   1) gemm2_k : fused  x@W_l -> xl , x@W_r -> xr  (fp32 math, bf16 stores)
//   2) counting-sort edges by dst: hist -> scanA -> scanB -> scanC -> scatter
//      scatter is XCD-range-partitioned: block b covers dst-range (b&7) and
//      edge-chunk (b>>3), so each 64B line of src_sorted is written by ONE
//      XCD's L2 and evicts once (kills the 105 MB -> ~10 MB write amplification).
//   3) agg_k   : one wave per dst node, fused online-softmax over its edges,
//                4-way edge ILP, bf16 gathers (256 B/wave/edge).

#define NEG_SLOPE 0.2f
#define EPS_F 1e-16f

static __device__ __forceinline__ unsigned f2bf(float f) {
    unsigned u = __float_as_uint(f);
    return (u + 0x7fffu + ((u >> 16) & 1u)) >> 16;   // RNE
}
static __device__ __forceinline__ float bf2f(unsigned h) {
    return __uint_as_float(h << 16);
}

// ------------- fused GEMM: xl = A*Wl, xr = A*Wr ; A[nrows x 128], W[128 x 128] -------------
__global__ __launch_bounds__(256) void gemm2_k(const float* __restrict__ A,
                                               const float* __restrict__ Wl,
                                               const float* __restrict__ Wr,
                                               unsigned* __restrict__ xlb,
                                               unsigned* __restrict__ xrb, int nrows) {
    __shared__ float xs[64][36];    // 64 rows x 32 k (+4 pad)
    __shared__ float wls[32][128];
    __shared__ float wrs[32][128];

    const int tid = threadIdx.x;
    const int ty = tid >> 4;   // 0..15 -> 4 rows
    const int tx = tid & 15;   // 0..15 -> cols tx*4..+3 and 64+tx*4..+3
    const int row0 = blockIdx.x * 64;

    float accl[4][8], accr[4][8];
#pragma unroll
    for (int i = 0; i < 4; ++i)
#pragma unroll
        for (int j = 0; j < 8; ++j) { accl[i][j] = 0.f; accr[i][j] = 0.f; }

    for (int kc = 0; kc < 4; ++kc) {
#pragma unroll
        for (int i = 0; i < 2; ++i) {
            int idx = tid + i * 256;
            int r = idx >> 3, kq = idx & 7;
            int gr = row0 + r;
            gr = gr < nrows ? gr : nrows - 1;
            *(float4*)(&xs[r][kq * 4]) = *(const float4*)(A + (size_t)gr * 128 + kc * 32 + kq * 4);
        }
#pragma unroll
        for (int i = 0; i < 4; ++i) {
            int idx = tid + i * 256;
            int k = idx >> 5, c4 = idx & 31;
            *(float4*)(&wls[k][c4 * 4]) = *(const float4*)(Wl + (size_t)(kc * 32 + k) * 128 + c4 * 4);
            *(float4*)(&wrs[k][c4 * 4]) = *(const float4*)(Wr + (size_t)(kc * 32 + k) * 128 + c4 * 4);
        }
        __syncthreads();

#pragma unroll 8
        for (int k = 0; k < 32; ++k) {
            float av[4];
            av[0] = xs[ty * 4 + 0][k];
            av[1] = xs[ty * 4 + 1][k];
            av[2] = xs[ty * 4 + 2][k];
            av[3] = xs[ty * 4 + 3][k];
            float4 l0 = *(float4*)(&wls[k][tx * 4]);
            float4 l1 = *(float4*)(&wls[k][64 + tx * 4]);
            float4 r0 = *(float4*)(&wrs[k][tx * 4]);
            float4 r1 = *(float4*)(&wrs[k][64 + tx * 4]);
            float lw[8] = {l0.x, l0.y, l0.z, l0.w, l1.x, l1.y, l1.z, l1.w};
            float rw[8] = {r0.x, r0.y, r0.z, r0.w, r1.x, r1.y, r1.z, r1.w};
#pragma unroll
            for (int i = 0; i < 4; ++i)
#pragma unroll
                for (int j = 0; j < 8; ++j) {
                    accl[i][j] = fmaf(av[i], lw[j], accl[i][j]);
                    accr[i][j] = fmaf(av[i], rw[j], accr[i][j]);
                }
        }
        __syncthreads();
    }

#pragma unroll
    for (int i = 0; i < 4; ++i) {
        int gr = row0 + ty * 4 + i;
        if (gr < nrows) {
            uint2 la = {f2bf(accl[i][0]) | (f2bf(accl[i][1]) << 16),
                        f2bf(accl[i][2]) | (f2bf(accl[i][3]) << 16)};
            uint2 lb = {f2bf(accl[i][4]) | (f2bf(accl[i][5]) << 16),
                        f2bf(accl[i][6]) | (f2bf(accl[i][7]) << 16)};
            uint2 ra = {f2bf(accr[i][0]) | (f2bf(accr[i][1]) << 16),
                        f2bf(accr[i][2]) | (f2bf(accr[i][3]) << 16)};
            uint2 rb = {f2bf(accr[i][4]) | (f2bf(accr[i][5]) << 16),
                        f2bf(accr[i][6]) | (f2bf(accr[i][7]) << 16)};
            *(uint2*)(xlb + (size_t)gr * 64 + tx * 2) = la;
            *(uint2*)(xlb + (size_t)gr * 64 + 32 + tx * 2) = lb;
            *(uint2*)(xrb + (size_t)gr * 64 + tx * 2) = ra;
            *(uint2*)(xrb + (size_t)gr * 64 + 32 + tx * 2) = rb;
        }
    }
}

// ---------------- counting sort of edges by dst (parallel 2-level scan) ----------------
__global__ void hist_k(const int* __restrict__ dst, int E, int* __restrict__ cnt) {
    int e = blockIdx.x * blockDim.x + threadIdx.x;
    if (e < E) atomicAdd(&cnt[dst[e]], 1);
}

#define SCAN_B 256
__global__ __launch_bounds__(SCAN_B) void scanA_k(const int* __restrict__ cnt, int n,
                                                  int* __restrict__ row_start,
                                                  int* __restrict__ bsum) {
    const int tid = threadIdx.x, lane = tid & 63, wid = tid >> 6;
    const int g = blockIdx.x * SCAN_B + tid;
    int v = (g < n) ? cnt[g] : 0;
    int inc = v;
#pragma unroll
    for (int d = 1; d < 64; d <<= 1) {
        int t = __shfl_up(inc, d);
        if (lane >= d) inc += t;
    }
    __shared__ int wsum[SCAN_B / 64];
    if (lane == 63) wsum[wid] = inc;
    __syncthreads();
    int add = 0;
    for (int w = 0; w < wid; ++w) add += wsum[w];
    inc += add;
    if (g < n) row_start[g] = inc - v;
    if (tid == SCAN_B - 1) bsum[blockIdx.x] = inc;
}

__global__ __launch_bounds__(512) void scanB_k(int* __restrict__ bsum, int nb) {
    const int tid = threadIdx.x, lane = tid & 63, wid = tid >> 6;
    int v = (tid < nb) ? bsum[tid] : 0;
    int inc = v;
#pragma unroll
    for (int d = 1; d < 64; d <<= 1) {
        int t = __shfl_up(inc, d);
        if (lane >= d) inc += t;
    }
    __shared__ int wsum[8];
    if (lane == 63) wsum[wid] = inc;
    __syncthreads();
    int add = 0;
    for (int w = 0; w < wid; ++w) add += wsum[w];
    inc += add;
    if (tid < nb) bsum[tid] = inc - v;
}

__global__ __launch_bounds__(SCAN_B) void scanC_k(int* __restrict__ row_start,
                                                  const int* __restrict__ bsum,
                                                  int* __restrict__ cursor, int n, int E) {
    const int g = blockIdx.x * SCAN_B + threadIdx.x;
    if (g < n) {
        int v = row_start[g] + bsum[blockIdx.x];
        row_start[g] = v;
        cursor[g] = v;
    }
    if (g == 0) row_start[n] = E;
}

// XCD-range-partitioned scatter: block b -> dst-range (b&7), edge-chunk (b>>3).
// Consecutive blockIdx round-robin across the 8 XCDs, so range r's writes stay
// in one XCD's L2; each src_sorted line accumulates all its stores, evicts once.
#define NRANGE 8
__global__ __launch_bounds__(256) void scatter_k(const int* __restrict__ src,
                                                 const int* __restrict__ dst, int E,
                                                 int rsz, int chunk_e,
                                                 int* __restrict__ cursor,
                                                 int* __restrict__ src_sorted) {
    const int r = blockIdx.x & (NRANGE - 1);
    const int c = blockIdx.x >> 3;
    const unsigned r_lo = (unsigned)(r * rsz);
    const int e0 = c * chunk_e;
    const int e1 = min(e0 + chunk_e, E);
    for (int e = e0 + (int)threadIdx.x; e < e1; e += 256) {
        int d = dst[e];
        if ((unsigned)d - r_lo < (unsigned)rsz) {
            int pos = atomicAdd(&cursor[d], 1);
            src_sorted[pos] = src[e];
        }
    }
}

// ---------------- fused online-softmax aggregation, 4-way edge ILP ----------------
__global__ __launch_bounds__(256) void agg_k(const unsigned* __restrict__ xlb,
                                             const unsigned* __restrict__ xrb,
                                             const float* __restrict__ att,
                                             const float* __restrict__ bias,
                                             const int* __restrict__ row_start,
                                             const int* __restrict__ src_sorted,
                                             int n, float* __restrict__ out) {
    const int wave = threadIdx.x >> 6;
    const int lane = threadIdx.x & 63;
    const int i = blockIdx.x * 4 + wave;
    if (i >= n) return;

    const int c0 = lane * 2;
    unsigned xrv = xrb[(size_t)i * 64 + lane];
    const float xr0 = bf2f(xrv & 0xffffu), xr1 = bf2f(xrv >> 16);
    const float at0 = att[c0], at1 = att[c0 + 1];

    const int k0 = row_start[i];
    const int k1 = row_start[i + 1];

    float m[4], l[4], A0[4], A1[4];
#pragma unroll
    for (int u = 0; u < 4; ++u) { m[u] = -INFINITY; l[u] = 0.f; A0[u] = 0.f; A1[u] = 0.f; }

    int k = k0;
    for (; k + 4 <= k1; k += 4) {
        int s[4];
#pragma unroll
        for (int u = 0; u < 4; ++u) s[u] = src_sorted[k + u];
        unsigned v[4];
#pragma unroll
        for (int u = 0; u < 4; ++u) v[u] = xlb[(size_t)s[u] * 64 + lane];
        float x0[4], x1[4], p[4];
#pragma unroll
        for (int u = 0; u < 4; ++u) {
            x0[u] = bf2f(v[u] & 0xffffu);
            x1[u] = bf2f(v[u] >> 16);
            float h0 = x0[u] + xr0;
            float h1 = x1[u] + xr1;
            h0 = h0 > 0.f ? h0 : NEG_SLOPE * h0;
            h1 = h1 > 0.f ? h1 : NEG_SLOPE * h1;
            p[u] = fmaf(h0, at0, h1 * at1);
        }
#pragma unroll
        for (int d = 1; d < 16; d <<= 1) {
#pragma unroll
            for (int u = 0; u < 4; ++u) p[u] += __shfl_xor(p[u], d);
        }
#pragma unroll
        for (int u = 0; u < 4; ++u) {
            float mn = fmaxf(m[u], p[u]);
            float sc = __expf(m[u] - mn);
            float w  = __expf(p[u] - mn);
            l[u]  = fmaf(l[u], sc, w);
            A0[u] = fmaf(A0[u], sc, w * x0[u]);
            A1[u] = fmaf(A1[u], sc, w * x1[u]);
            m[u] = mn;
        }
    }
    for (; k < k1; ++k) {
        int s = src_sorted[k];
        unsigned v = xlb[(size_t)s * 64 + lane];
        float x0 = bf2f(v & 0xffffu), x1 = bf2f(v >> 16);
        float h0 = x0 + xr0, h1 = x1 + xr1;
        h0 = h0 > 0.f ? h0 : NEG_SLOPE * h0;
        h1 = h1 > 0.f ? h1 : NEG_SLOPE * h1;
        float p = fmaf(h0, at0, h1 * at1);
        p += __shfl_xor(p, 1);
        p += __shfl_xor(p, 2);
        p += __shfl_xor(p, 4);
        p += __shfl_xor(p, 8);
        float mn = fmaxf(m[0], p);
        float sc = __expf(m[0] - mn);
        float w  = __expf(p - mn);
        l[0]  = fmaf(l[0], sc, w);
        A0[0] = fmaf(A0[0], sc, w * x0);
        A1[0] = fmaf(A1[0], sc, w * x1);
        m[0] = mn;
    }

#pragma unroll
    for (int u = 1; u < 4; ++u) {
        if (m[u] > -INFINITY) {
            float mn = fmaxf(m[0], m[u]);
            float s0 = __expf(m[0] - mn);
            float s1 = __expf(m[u] - mn);
            l[0]  = l[0] * s0 + l[u] * s1;
            A0[0] = A0[0] * s0 + A0[u] * s1;
            A1[0] = A1[0] * s0 + A1[u] * s1;
            m[0] = mn;
        }
    }

    float inv = 1.f / (l[0] + EPS_F);
    float2 o = {fmaf(A0[0], inv, bias[c0]), fmaf(A1[0], inv, bias[c0 + 1])};
    *(float2*)(out + (size_t)i * 128 + c0) = o;
}

// ---------------- launch ----------------
extern "C" void kernel_launch(void* const* d_in, const int* in_sizes, int n_in,
                              void* d_out, int out_size, void* d_ws, size_t ws_size,
                              hipStream_t stream) {
    const float* x    = (const float*)d_in[0];
    const int*   ei   = (const int*)d_in[1];
    const float* W_l  = (const float*)d_in[2];
    const float* W_r  = (const float*)d_in[3];
    const float* att  = (const float*)d_in[4];
    const float* bias = (const float*)d_in[5];
    float* out = (float*)d_out;

    const int N = in_sizes[0] / 128;
    const int E = in_sizes[1] / 2;
    const int* src = ei;
    const int* dst = ei + E;

    char* ws = (char*)d_ws;
    size_t off = 0;
    auto alloc = [&](size_t bytes) {
        void* p = ws + off;
        off += (bytes + 15) & ~(size_t)15;
        return p;
    };
    unsigned* xlb     = (unsigned*)alloc((size_t)N * 64 * 4);   // bf16-packed
    unsigned* xrb     = (unsigned*)alloc((size_t)N * 64 * 4);
    int* cnt          = (int*)alloc((size_t)N * 4);
    int* row_start    = (int*)alloc((size_t)(N + 1) * 4);
    int* cursor       = (int*)alloc((size_t)N * 4);
    const int nsb = (N + SCAN_B - 1) / SCAN_B;
    int* bsum         = (int*)alloc((size_t)nsb * 4);
    int* src_sorted   = (int*)alloc((size_t)E * 4);
    (void)ws_size;

    hipMemsetAsync(cnt, 0, (size_t)N * 4, stream);

    gemm2_k<<<(N + 63) / 64, 256, 0, stream>>>(x, W_l, W_r, xlb, xrb, N);

    hist_k<<<(E + 255) / 256, 256, 0, stream>>>(dst, E, cnt);
    scanA_k<<<nsb, SCAN_B, 0, stream>>>(cnt, N, row_start, bsum);
    scanB_k<<<1, 512, 0, stream>>>(bsum, nsb);
    scanC_k<<<nsb, SCAN_B, 0, stream>>>(row_start, bsum, cursor, N, E);

    const int rsz = (N + NRANGE - 1) / NRANGE;       // dst-range size per XCD
    const int nchunks = 128;
    const int chunk_e = (E + nchunks - 1) / nchunks;
    scatter_k<<<NRANGE * nchunks, 256, 0, stream>>>(src, dst, E, rsz, chunk_e,
                                                    cursor, src_sorted);

    agg_k<<<(N + 3) / 4, 256, 0, stream>>>(xlb, xrb, att, bias, row_start, src_sorted, N, out);
}